// Round 1
// baseline (262.711 us; speedup 1.0000x reference)
//
#include <hip/hip_runtime.h>
#include <math.h>

constexpr int   CDIM  = 256;     // channels
constexpr int   HWSP  = 4096;    // H*W = 64*64 (fixed problem shape)
constexpr int   PPB   = 64;      // spatial positions per block
constexpr float SQRTC = 0.031622776601683794f;  // sqrt(0.001)
constexpr float EPSR  = 1e-6f;

// ---- Kernel 0: build doubled circular-conv kernel w2[512] from phi ----
// v0 = irfft(rfft(u1) * Hf[:129], n=256)  ==  circular_conv(u1, w)
// w[d] = (1/256)[ cos(10*phi[0]) + (-1)^d cos(10*phi[128])
//                 + 2 * sum_{k=1..127} cos(10*phi[k] + 2*pi*k*d/256) ]
// (irfft discards the imaginary parts of the DC and Nyquist bins.)
__global__ void build_w2_kernel(const float* __restrict__ phi,
                                float* __restrict__ w2) {
    const int d = threadIdx.x;                  // 0..255
    const float step = 6.283185307179586f / 256.0f;
    double s = 0.0;
    for (int k = 1; k <= 127; ++k) {
        int kd = (k * d) & 255;                 // exact mod-2pi angle reduction
        float ang = 10.0f * phi[k] + step * (float)kd;
        s += 2.0 * (double)cosf(ang);
    }
    s += (double)cosf(10.0f * phi[0]);
    double c128 = (double)cosf(10.0f * phi[128]);
    s += (d & 1) ? -c128 : c128;
    float w = (float)(s * (1.0 / 256.0));
    w2[d]       = w;
    w2[d + 256] = w;                            // doubled: wrap-free indexing
}

// radial Fourier gate: a0 + sum_{n=1..16} a[n-1]*cos(r*n) + b[n-1]*sin(r*n)
// (OMEGA = 1); angle-addition recurrence: 1 sincos + 16 complex rotations
__device__ inline float fourier_gate(float r, float A0,
                                     const float* __restrict__ a,
                                     const float* __restrict__ b) {
    float sn, cs;
    sincosf(r, &sn, &cs);
    float c = cs, s = sn, f = A0;
    #pragma unroll
    for (int n = 0; n < 16; ++n) {
        f = fmaf(a[n], c, f);
        f = fmaf(b[n], s, f);
        float c2 = fmaf(c, cs, -s * sn);
        float s2 = fmaf(s, cs,  c * sn);
        c = c2; s = s2;
    }
    return f;
}

__global__ __launch_bounds__(256, 2)
void fused_kernel(const float* __restrict__ x,
                  const float* __restrict__ a0_1, const float* __restrict__ a1,
                  const float* __restrict__ b1,
                  const float* __restrict__ a0_2, const float* __restrict__ a2,
                  const float* __restrict__ b2,
                  const float* __restrict__ alpha, const float* __restrict__ beta,
                  const float* __restrict__ w2,
                  float* __restrict__ out) {
    __shared__ float xl[CDIM][PPB];             // exactly 64 KB
    const int t = threadIdx.x;
    const int p = t & 63;                       // lane = spatial position
    const int g = t >> 6;                       // wave id = output-channel quarter
    const int b  = blockIdx.x >> 6;             // HWSP/PPB = 64 blocks per batch
    const int s0 = (blockIdx.x & 63) * PPB;
    const float* xb = x + ((size_t)b * CDIM) * HWSP + s0;

    // transpose-load tile: coalesced 256B segments per wave-instruction
    for (int c = g; c < CDIM; c += 4)
        xl[c][p] = xb[(size_t)c * HWSP + p];
    __syncthreads();

    // ---- pre-norm of h0 (redundant full sum per thread; stride-1 LDS) ----
    float n0sq = 0.f;
    for (int c = 0; c < CDIM; ++c) {
        float v = xl[c][p];
        n0sq = fmaf(v, v, n0sq);
    }
    float n0  = sqrtf(n0sq);
    float rn0 = fmaxf(n0, EPSR);
    float arg = fminf(SQRTC * rn0, 1.0f - 1e-5f);
    float ls  = atanhf(arg) / (SQRTC * rn0);    // log-map scale: u = ls*h0
    float r1  = fmaxf(ls * n0, EPSR);           // ||u||
    float f1  = fourier_gate(r1, a0_1[0], a1, b1);
    float s1  = ls * f1;                        // u1 = s1 * h0 (pulled out by linearity)

    // ---- circulant matvec: dot[j] = sum_c w[(j-c)&255] * h0[c] ----
    // jbase is wave-uniform -> w reads become s_load (scalar operand FMAs)
    float acc[64];
    #pragma unroll
    for (int j = 0; j < 64; ++j) acc[j] = 0.f;
    const int jbase = __builtin_amdgcn_readfirstlane(g << 6);
    for (int c = 0; c < CDIM; ++c) {
        float hv = xl[c][p];                    // 1 LDS read per 64 FMAs
        const float* __restrict__ wr = w2 + ((jbase - c) & 255);
        #pragma unroll
        for (int j = 0; j < 64; ++j)
            acc[j] = fmaf(hv, wr[j], acc[j]);
    }

    // ---- ||dot|| reduction across 4 waves (alias scratch onto dead xl) ----
    float ssv = 0.f;
    #pragma unroll
    for (int j = 0; j < 64; ++j) ssv = fmaf(acc[j], acc[j], ssv);
    __syncthreads();                            // all xl reads finished
    xl[g][p] = ssv;                             // rows 0..3 reused as scratch
    __syncthreads();
    float nvsq = xl[0][p] + xl[1][p] + xl[2][p] + xl[3][p];

    float nv  = sqrtf(nvsq) * fabsf(s1);        // ||v0||, v0 = s1*dot
    float r2  = fmaxf(nv, EPSR);
    float f2  = fourier_gate(r2, a0_2[0], a2, b2);
    float rn1 = fmaxf(fabsf(f2) * nv, EPSR);    // ||v1|| = |f2|*||v0||
    float es  = tanhf(SQRTC * rn1) / (SQRTC * rn1);  // exp-map scale
    float so  = alpha[0] * es * f2 * s1;        // out = so*dot + beta*h0
    float bb  = beta[0];

    float* ob = out + ((size_t)b * CDIM) * HWSP + s0;
    #pragma unroll
    for (int j = 0; j < 64; ++j) {
        int ch = jbase + j;
        // beta*h0 re-read from global (L2-hot; xl rows 0..3 were clobbered)
        ob[(size_t)ch * HWSP + p] =
            fmaf(so, acc[j], bb * xb[(size_t)ch * HWSP + p]);
    }
}

extern "C" void kernel_launch(void* const* d_in, const int* in_sizes, int n_in,
                              void* d_out, int out_size, void* d_ws, size_t ws_size,
                              hipStream_t stream) {
    const float* x     = (const float*)d_in[0];
    const float* a0_1  = (const float*)d_in[1];
    const float* a1    = (const float*)d_in[2];
    const float* b1    = (const float*)d_in[3];
    const float* a0_2  = (const float*)d_in[4];
    const float* a2    = (const float*)d_in[5];
    const float* b2    = (const float*)d_in[6];
    const float* phi   = (const float*)d_in[7];
    const float* alpha = (const float*)d_in[8];
    const float* beta  = (const float*)d_in[9];

    float* w2 = (float*)d_ws;                   // 512 floats of scratch

    build_w2_kernel<<<1, 256, 0, stream>>>(phi, w2);

    const int B = in_sizes[0] / (CDIM * HWSP);  // 32
    fused_kernel<<<dim3(B * (HWSP / PPB)), dim3(256), 0, stream>>>(
        x, a0_1, a1, b1, a0_2, a2, b2, alpha, beta, w2, (float*)d_out);
}

// Round 2
// 93.297 us; speedup vs baseline: 2.8158x; 2.8158x over previous
//
#include <hip/hip_runtime.h>
#include <math.h>

typedef __attribute__((ext_vector_type(8))) unsigned short ushort8;
typedef __attribute__((ext_vector_type(8))) __bf16 bf16x8;
typedef __attribute__((ext_vector_type(4))) float f32x4;

constexpr int   CDIM  = 256;     // channels
constexpr int   HWSP  = 4096;    // H*W
constexpr int   PPB   = 64;      // positions per block
constexpr float SQRTC = 0.031622776601683794f;  // sqrt(0.001)
constexpr float EPSR  = 1e-6f;

__device__ inline unsigned short f2bf(float x) {  // RNE f32 -> bf16
    unsigned int u = __float_as_uint(x);
    u += 0x7FFFu + ((u >> 16) & 1u);
    return (unsigned short)(u >> 16);
}
__device__ inline float bf2f(unsigned short v) {
    return __uint_as_float(((unsigned int)v) << 16);
}

// ---- Kernel 0: circular-conv kernel w[256] from phi ----
// irfft(rfft(u1)*Hf[:129]) == circular_conv(u1, w);  irfft drops imag at DC/Nyq.
__global__ void build_w_kernel(const float* __restrict__ phi,
                               float* __restrict__ w) {
    const int d = threadIdx.x;                  // 0..255
    const float step = 6.283185307179586f / 256.0f;
    double s = 0.0;
    for (int k = 1; k <= 127; ++k) {
        int kd = (k * d) & 255;                 // exact mod-2pi reduction
        float ang = 10.0f * phi[k] + step * (float)kd;
        s += 2.0 * (double)cosf(ang);
    }
    s += (double)cosf(10.0f * phi[0]);
    double c128 = (double)cosf(10.0f * phi[128]);
    s += (d & 1) ? -c128 : c128;
    w[d] = (float)(s * (1.0 / 256.0));
}

// ---- Kernel 1: materialize circulant W as bf16 [256][256] row-major ----
__global__ void build_wbf_kernel(const float* __restrict__ w,
                                 unsigned short* __restrict__ wbf) {
    const int j = blockIdx.x;                   // out channel (row)
    const int c = threadIdx.x;                  // in channel (col)
    wbf[j * CDIM + c] = f2bf(w[(j - c) & 255]);
}

// radial Fourier gate: a0 + sum a[n]cos(r(n+1)) + b[n]sin(r(n+1))
__device__ inline float fourier_gate(float r, float A0,
                                     const float* __restrict__ a,
                                     const float* __restrict__ b) {
    float sn, cs;
    sincosf(r, &sn, &cs);
    float c = cs, s = sn, f = A0;
    #pragma unroll
    for (int n = 0; n < 16; ++n) {
        f = fmaf(a[n], c, f);
        f = fmaf(b[n], s, f);
        float c2 = fmaf(c, cs, -s * sn);
        float s2 = fmaf(s, cs,  c * sn);
        c = c2; s = s2;
    }
    return f;
}

__global__ __launch_bounds__(256, 3)
void fused_mfma(const float* __restrict__ x,
                const float* __restrict__ a0_1, const float* __restrict__ a1,
                const float* __restrict__ b1,
                const float* __restrict__ a0_2, const float* __restrict__ a2,
                const float* __restrict__ b2,
                const float* __restrict__ alpha, const float* __restrict__ beta,
                const unsigned short* __restrict__ wbf,
                float* __restrict__ out) {
    __shared__ __align__(16) unsigned short Xl[PPB][CDIM];  // 32 KB, swizzled
    __shared__ float ns[4][PPB];
    __shared__ float sc2[4][PPB];
    __shared__ float s1buf[PPB];
    __shared__ float sobuf[PPB];

    const int t  = threadIdx.x;
    const int l  = t & 63;
    const int g  = t >> 6;                      // wave id = outch quarter
    const int b  = blockIdx.x >> 6;
    const int s0 = (blockIdx.x & 63) * PPB;
    const float* xb = x + (size_t)b * CDIM * HWSP + s0;

    // ---- stage X tile -> bf16 LDS [pos][ch^((pos&7)<<3)]; f32 norm partial ----
    {
        const int p   = l;
        const int swz = (p & 7) << 3;
        float n0sq = 0.f;
        #pragma unroll
        for (int k = 0; k < 8; ++k) {
            const int ch0 = (g + 4 * k) * 8;    // channel octet
            float v[8];
            #pragma unroll
            for (int j = 0; j < 8; ++j)
                v[j] = xb[(size_t)(ch0 + j) * HWSP + p];   // coalesced 256B
            ushort8 u;
            #pragma unroll
            for (int j = 0; j < 8; ++j) {
                n0sq = fmaf(v[j], v[j], n0sq);
                u[j] = f2bf(v[j]);
            }
            *reinterpret_cast<ushort8*>(&Xl[p][ch0 ^ swz]) = u;
        }
        ns[g][p] = n0sq;
    }
    __syncthreads();

    // ---- scalars pass 1 (wave 0 only, uniform): log-map scale * gate1 ----
    if (t < PPB) {
        float nsq = ns[0][t] + ns[1][t] + ns[2][t] + ns[3][t];
        float n0  = sqrtf(nsq);
        float rn0 = fmaxf(n0, EPSR);
        float arg = fminf(SQRTC * rn0, 1.0f - 1e-5f);
        float ls  = atanhf(arg) / (SQRTC * rn0);
        float r1  = fmaxf(ls * n0, EPSR);
        s1buf[t]  = ls * fourier_gate(r1, a0_1[0], a1, b1);
    }

    // ---- MFMA GEMM: D[outch][pos] = W . h0  (bf16 in, f32 acc) ----
    const int lr = l & 15;
    const int lk = l >> 4;
    const int jbase = g * 64;
    f32x4 acc[4][4];
    #pragma unroll
    for (int m = 0; m < 4; ++m)
        #pragma unroll
        for (int n = 0; n < 4; ++n)
            acc[m][n] = f32x4{0.f, 0.f, 0.f, 0.f};

    #pragma unroll
    for (int ks = 0; ks < 8; ++ks) {
        const int kb = ks * 32 + lk * 8;
        bf16x8 af[4], bfr[4];
        #pragma unroll
        for (int m = 0; m < 4; ++m) {           // A: W rows (global, L2-hot)
            const int row = jbase + m * 16 + lr;
            af[m] = __builtin_bit_cast(bf16x8,
                *reinterpret_cast<const ushort8*>(&wbf[row * CDIM + kb]));
        }
        #pragma unroll
        for (int n = 0; n < 4; ++n) {           // B: X tile (LDS b128)
            const int pos = n * 16 + lr;
            const int ch  = kb ^ ((pos & 7) << 3);
            bfr[n] = __builtin_bit_cast(bf16x8,
                *reinterpret_cast<const ushort8*>(&Xl[pos][ch]));
        }
        #pragma unroll
        for (int m = 0; m < 4; ++m)
            #pragma unroll
            for (int n = 0; n < 4; ++n)
                acc[m][n] = __builtin_amdgcn_mfma_f32_16x16x32_bf16(
                    af[m], bfr[n], acc[m][n], 0, 0, 0);
    }

    // ---- ||dot||^2 per position: per-lane partials + xor-shuffle + LDS ----
    {
        float part[4];
        #pragma unroll
        for (int n = 0; n < 4; ++n) {
            float s = 0.f;
            #pragma unroll
            for (int m = 0; m < 4; ++m)
                #pragma unroll
                for (int r = 0; r < 4; ++r)
                    s = fmaf(acc[m][n][r], acc[m][n][r], s);
            s += __shfl_xor(s, 16, 64);
            s += __shfl_xor(s, 32, 64);
            part[n] = s;
        }
        if (lk == 0) {
            #pragma unroll
            for (int n = 0; n < 4; ++n) sc2[g][n * 16 + lr] = part[n];
        }
    }
    __syncthreads();

    // ---- scalars pass 2: gate2 + exp-map + alpha ----
    if (t < PPB) {
        float nvsq = sc2[0][t] + sc2[1][t] + sc2[2][t] + sc2[3][t];
        float s1   = s1buf[t];
        float nv   = sqrtf(nvsq) * fabsf(s1);   // ||v0||, v0 = s1*dot
        float r2   = fmaxf(nv, EPSR);
        float f2   = fourier_gate(r2, a0_2[0], a2, b2);
        float rn1  = fmaxf(fabsf(f2) * nv, EPSR);
        float es   = tanhf(SQRTC * rn1) / (SQRTC * rn1);
        sobuf[t]   = alpha[0] * es * f2 * s1;   // out = so*dot + beta*h0
    }
    __syncthreads();

    // ---- scale + store (aligned 64B segments; full lines, no RMW) ----
    const float bb = beta[0];
    float* ob = out + (size_t)b * CDIM * HWSP + s0;
    if (bb == 0.f) {                            // uniform branch
        #pragma unroll
        for (int m = 0; m < 4; ++m)
            #pragma unroll
            for (int r = 0; r < 4; ++r)
                #pragma unroll
                for (int n = 0; n < 4; ++n) {
                    const int row = jbase + m * 16 + lk * 4 + r;
                    const int pos = n * 16 + lr;
                    ob[(size_t)row * HWSP + pos] = sobuf[pos] * acc[m][n][r];
                }
    } else {                                    // residual from bf16 LDS copy
        #pragma unroll
        for (int m = 0; m < 4; ++m)
            #pragma unroll
            for (int r = 0; r < 4; ++r)
                #pragma unroll
                for (int n = 0; n < 4; ++n) {
                    const int row = jbase + m * 16 + lk * 4 + r;
                    const int pos = n * 16 + lr;
                    const float h0 = bf2f(Xl[pos][row ^ ((pos & 7) << 3)]);
                    ob[(size_t)row * HWSP + pos] =
                        fmaf(bb, h0, sobuf[pos] * acc[m][n][r]);
                }
    }
}

extern "C" void kernel_launch(void* const* d_in, const int* in_sizes, int n_in,
                              void* d_out, int out_size, void* d_ws, size_t ws_size,
                              hipStream_t stream) {
    const float* x     = (const float*)d_in[0];
    const float* a0_1  = (const float*)d_in[1];
    const float* a1    = (const float*)d_in[2];
    const float* b1    = (const float*)d_in[3];
    const float* a0_2  = (const float*)d_in[4];
    const float* a2    = (const float*)d_in[5];
    const float* b2    = (const float*)d_in[6];
    const float* phi   = (const float*)d_in[7];
    const float* alpha = (const float*)d_in[8];
    const float* beta  = (const float*)d_in[9];

    float*          wtab = (float*)d_ws;                    // 256 f32
    unsigned short* wbf  = (unsigned short*)((char*)d_ws + 1024);  // 128 KB bf16

    build_w_kernel<<<1, 256, 0, stream>>>(phi, wtab);
    build_wbf_kernel<<<CDIM, CDIM, 0, stream>>>(wtab, wbf);

    const int B = in_sizes[0] / (CDIM * HWSP);              // 32
    fused_mfma<<<dim3(B * (HWSP / PPB)), dim3(256), 0, stream>>>(
        x, a0_1, a1, b1, a0_2, a2, b2, alpha, beta, wbf, (float*)d_out);
}

// Round 3
// 81.861 us; speedup vs baseline: 3.2092x; 1.1397x over previous
//
#include <hip/hip_runtime.h>
#include <math.h>

typedef __attribute__((ext_vector_type(8))) unsigned short ushort8;
typedef __attribute__((ext_vector_type(8))) __bf16 bf16x8;
typedef __attribute__((ext_vector_type(4))) float f32x4;

constexpr int   CDIM  = 256;     // channels
constexpr int   HWSP  = 4096;    // H*W
constexpr int   PPB   = 64;      // positions per block
constexpr float SQRTC = 0.031622776601683794f;  // sqrt(0.001)
constexpr float EPSR  = 1e-6f;

__device__ inline unsigned short f2bf(float x) {  // RNE f32 -> bf16
    unsigned int u = __float_as_uint(x);
    u += 0x7FFFu + ((u >> 16) & 1u);
    return (unsigned short)(u >> 16);
}

// ---- builder: w[256] (circular-conv kernel) -> Wpk in per-lane MFMA B-frag order
// Wpk[ks(8)][tile(16)][lane(64)][j(8)], value = w[(outch-ch)&255],
// outch = tile*16 + (lane&15), ch = ks*32 + (lane>>4)*8 + j.
__global__ void build_wpk(const float* __restrict__ phi,
                          unsigned short* __restrict__ wpk) {
    __shared__ float w[256];
    const int d = threadIdx.x;
    {
        const float step = 6.283185307179586f / 256.0f;
        double s = 0.0;
        for (int k = 1; k <= 127; ++k) {
            int kd = (k * d) & 255;             // exact mod-2pi reduction
            s += 2.0 * (double)cosf(10.0f * phi[k] + step * (float)kd);
        }
        s += (double)cosf(10.0f * phi[0]);
        double c128 = (double)cosf(10.0f * phi[128]);
        s += (d & 1) ? -c128 : c128;
        w[d] = (float)(s * (1.0 / 256.0));      // irfft drops imag at DC/Nyq
    }
    __syncthreads();
    const int l = d & 63, q = d >> 6;
    for (int blk = q; blk < 128; blk += 4) {    // blk = ks*16 + tile
        const int outc = (blk & 15) * 16 + (l & 15);
        const int ch0  = (blk >> 4) * 32 + (l >> 4) * 8;
        ushort8 u;
        #pragma unroll
        for (int j = 0; j < 8; ++j)
            u[j] = f2bf(w[(outc - (ch0 + j)) & 255]);
        *reinterpret_cast<ushort8*>(&wpk[(size_t)(blk * 64 + l) * 8]) = u;
    }
}

// radial Fourier gate: a0 + sum_{n=1..16} a[n-1]cos(rn) + b[n-1]sin(rn)
__device__ inline float fourier_gate(float r, float A0,
                                     const float* __restrict__ a,
                                     const float* __restrict__ b) {
    float sn, cs;
    sincosf(r, &sn, &cs);
    float c = cs, s = sn, f = A0;
    #pragma unroll
    for (int n = 0; n < 16; ++n) {
        f = fmaf(a[n], c, f);
        f = fmaf(b[n], s, f);
        float c2 = fmaf(c, cs, -s * sn);
        float s2 = fmaf(s, cs,  c * sn);
        c = c2; s = s2;
    }
    return f;
}

__global__ __launch_bounds__(256, 4)
void fused_mfma(const float* __restrict__ x,
                const float* __restrict__ a0_1, const float* __restrict__ a1,
                const float* __restrict__ b1,
                const float* __restrict__ a0_2, const float* __restrict__ a2,
                const float* __restrict__ b2,
                const float* __restrict__ phi,
                const float* __restrict__ alpha, const float* __restrict__ beta,
                const unsigned short* __restrict__ wpk,
                float* __restrict__ out) {
    __shared__ __align__(16) unsigned short Xl[PPB][CDIM];  // 32 KB, ch ^ (pos&15)<<3
    __shared__ __align__(16) float stats[3][4][PPB];        // nsq / S0 / S_alt
    __shared__ __align__(16) float sobuf[PPB];

    const int t  = threadIdx.x;
    const int l  = t & 63;
    const int g  = t >> 6;
    const int lr = l & 15;
    const int lk = l >> 4;
    const int b  = blockIdx.x >> 6;
    const int s0 = (blockIdx.x & 63) * PPB;
    const float* xb = x + (size_t)b * CDIM * HWSP + s0;

    // ---- stage: float4 loads (1KB/wave-instr), reg transpose, b128 LDS writes ----
    // thread = (channel octet co, position quad posq); f32 stats pre-rounding.
    f32x4 vns = {0.f,0.f,0.f,0.f}, vs0 = {0.f,0.f,0.f,0.f}, vsa = {0.f,0.f,0.f,0.f};
    const int posq = t & 15;
    #pragma unroll
    for (int i = 0; i < 2; ++i) {
        const int co = i * 16 + (t >> 4);       // channel octet 0..31
        f32x4 v[8];
        #pragma unroll
        for (int j = 0; j < 8; ++j)
            v[j] = *reinterpret_cast<const f32x4*>(
                       &xb[(size_t)(co * 8 + j) * HWSP + posq * 4]);
        #pragma unroll
        for (int j = 0; j < 8; ++j) {
            vns += v[j] * v[j];
            vs0 += v[j];
            vsa  = (j & 1) ? vsa - v[j] : vsa + v[j];
        }
        #pragma unroll
        for (int r = 0; r < 4; ++r) {           // in-register 8x4 transpose
            ushort8 u;
            #pragma unroll
            for (int j = 0; j < 8; ++j) u[j] = f2bf(v[j][r]);
            const int pos = posq * 4 + r;
            *reinterpret_cast<ushort8*>(&Xl[pos][(co * 8) ^ ((pos & 15) << 3)]) = u;
        }
    }
    // reduce over the 4 lanes sharing posq (l^16, l^32), then lk==0 writes
    #pragma unroll
    for (int r = 0; r < 4; ++r) {
        float aa = vns[r], ss = vs0[r], mm = vsa[r];
        aa += __shfl_xor(aa, 16, 64); aa += __shfl_xor(aa, 32, 64);
        ss += __shfl_xor(ss, 16, 64); ss += __shfl_xor(ss, 32, 64);
        mm += __shfl_xor(mm, 16, 64); mm += __shfl_xor(mm, 32, 64);
        vns[r] = aa; vs0[r] = ss; vsa[r] = mm;
    }
    if (lk == 0) {
        *reinterpret_cast<f32x4*>(&stats[0][g][posq * 4]) = vns;
        *reinterpret_cast<f32x4*>(&stats[1][g][posq * 4]) = vs0;
        *reinterpret_cast<f32x4*>(&stats[2][g][posq * 4]) = vsa;
    }
    __syncthreads();

    // ---- single scalar pass (wave 0), hidden under waves 1-3's MFMA ----
    // Parseval: ||dot||^2 = nsq - [S0^2 sin^2(10*phi0) + Sa^2 sin^2(10*phi128)]/256
    if (t < PPB) {
        float nsq = stats[0][0][t] + stats[0][1][t] + stats[0][2][t] + stats[0][3][t];
        float S0  = stats[1][0][t] + stats[1][1][t] + stats[1][2][t] + stats[1][3][t];
        float Sa  = stats[2][0][t] + stats[2][1][t] + stats[2][2][t] + stats[2][3][t];
        float sin0 = sinf(10.0f * phi[0]);
        float sinN = sinf(10.0f * phi[128]);
        float n0  = sqrtf(nsq);
        float rn0 = fmaxf(n0, EPSR);
        float arg = fminf(SQRTC * rn0, 1.0f - 1e-5f);
        float ls  = atanhf(arg) / (SQRTC * rn0);
        float r1  = fmaxf(ls * n0, EPSR);
        float s1  = ls * fourier_gate(r1, a0_1[0], a1, b1);
        float dn2 = fmaxf(nsq - (S0 * S0 * sin0 * sin0 + Sa * Sa * sinN * sinN)
                                 * (1.0f / 256.0f), 0.f);
        float nv  = sqrtf(dn2) * fabsf(s1);     // ||v0||
        float r2  = fmaxf(nv, EPSR);
        float f2  = fourier_gate(r2, a0_2[0], a2, b2);
        float rn1 = fmaxf(fabsf(f2) * nv, EPSR);
        float es  = tanhf(SQRTC * rn1) / (SQRTC * rn1);
        sobuf[t]  = alpha[0] * es * f2 * s1;    // out = so*dot + beta*h0
    }

    // ---- MFMA: D[pos][outch] = X . Wt  (A = X-tile from LDS, B = W packed) ----
    f32x4 acc[4][4];
    #pragma unroll
    for (int m = 0; m < 4; ++m)
        #pragma unroll
        for (int n = 0; n < 4; ++n)
            acc[m][n] = f32x4{0.f, 0.f, 0.f, 0.f};

    #pragma unroll
    for (int ks = 0; ks < 8; ++ks) {
        const int kb = ks * 32 + lk * 8;
        bf16x8 af[4], bw[4];
        #pragma unroll
        for (int m = 0; m < 4; ++m) {           // A: X rows (pos), LDS b128
            const int pos = m * 16 + lr;
            af[m] = __builtin_bit_cast(bf16x8,
                *reinterpret_cast<const ushort8*>(&Xl[pos][kb ^ ((pos & 15) << 3)]));
        }
        #pragma unroll
        for (int n = 0; n < 4; ++n)             // B: W frags, coalesced L2-hot
            bw[n] = __builtin_bit_cast(bf16x8,
                *reinterpret_cast<const ushort8*>(
                    &wpk[(size_t)((ks * 16 + g * 4 + n) * 64 + l) * 8]));
        #pragma unroll
        for (int m = 0; m < 4; ++m)
            #pragma unroll
            for (int n = 0; n < 4; ++n)
                acc[m][n] = __builtin_amdgcn_mfma_f32_16x16x32_bf16(
                    af[m], bw[n], acc[m][n], 0, 0, 0);
    }
    __syncthreads();                            // sobuf ready

    // ---- epilogue: r = 4 consecutive positions -> dwordx4 stores from acc ----
    const float bb = beta[0];
    float* ob = out + (size_t)b * CDIM * HWSP + s0;
    if (bb == 0.f) {                            // uniform branch
        #pragma unroll
        for (int m = 0; m < 4; ++m) {
            const int p0 = m * 16 + lk * 4;
            const f32x4 sob = *reinterpret_cast<const f32x4*>(&sobuf[p0]);
            #pragma unroll
            for (int n = 0; n < 4; ++n) {
                const int outc = (g * 4 + n) * 16 + lr;
                f32x4 vv = acc[m][n] * sob;
                *reinterpret_cast<f32x4*>(&ob[(size_t)outc * HWSP + p0]) = vv;
            }
        }
    } else {                                    // residual path (x re-read, L2-hot)
        #pragma unroll
        for (int m = 0; m < 4; ++m) {
            const int p0 = m * 16 + lk * 4;
            const f32x4 sob = *reinterpret_cast<const f32x4*>(&sobuf[p0]);
            #pragma unroll
            for (int n = 0; n < 4; ++n) {
                const int outc = (g * 4 + n) * 16 + lr;
                const f32x4 xv = *reinterpret_cast<const f32x4*>(
                                     &xb[(size_t)outc * HWSP + p0]);
                f32x4 vv = acc[m][n] * sob + bb * xv;
                *reinterpret_cast<f32x4*>(&ob[(size_t)outc * HWSP + p0]) = vv;
            }
        }
    }
}

extern "C" void kernel_launch(void* const* d_in, const int* in_sizes, int n_in,
                              void* d_out, int out_size, void* d_ws, size_t ws_size,
                              hipStream_t stream) {
    const float* x     = (const float*)d_in[0];
    const float* a0_1  = (const float*)d_in[1];
    const float* a1    = (const float*)d_in[2];
    const float* b1    = (const float*)d_in[3];
    const float* a0_2  = (const float*)d_in[4];
    const float* a2    = (const float*)d_in[5];
    const float* b2    = (const float*)d_in[6];
    const float* phi   = (const float*)d_in[7];
    const float* alpha = (const float*)d_in[8];
    const float* beta  = (const float*)d_in[9];

    unsigned short* wpk = (unsigned short*)d_ws;            // 128 KB

    build_wpk<<<1, 256, 0, stream>>>(phi, wpk);

    const int B = in_sizes[0] / (CDIM * HWSP);              // 32
    fused_mfma<<<dim3(B * (HWSP / PPB)), dim3(256), 0, stream>>>(
        x, a0_1, a1, b1, a0_2, a2, b2, phi, alpha, beta, wpk, (float*)d_out);
}